// Round 12
// baseline (373.490 us; speedup 1.0000x reference)
//
#include <hip/hip_runtime.h>

#define BB 4
#define CC 96
#define HH 64
#define WW 64
#define LL 4096
#define KK 3
#define RR 6
#define NN 16

__device__ __forceinline__ float geluf(float x){
    return 0.5f * x * (1.0f + erff(x * 0.70710678118654752f));
}
__device__ __forceinline__ float softplusf(float x){
    return fmaxf(x, 0.0f) + log1pf(expf(-fabsf(x)));
}
__device__ __forceinline__ float sigmoidf(float x){
    return 1.0f / (1.0f + expf(-x));
}

// ---------------- Kernel A: per-(b,c) spatial mean ----------------
__global__ __launch_bounds__(256) void k_mean(const float* __restrict__ x, float* __restrict__ xc){
    int bc = blockIdx.x; // 0..B*C-1
    const float* p = x + (size_t)bc * LL;
    float s = 0.f;
    for (int i = threadIdx.x; i < LL; i += 256) s += p[i];
    __shared__ float red[256];
    red[threadIdx.x] = s; __syncthreads();
    for (int st = 128; st > 0; st >>= 1){
        if (threadIdx.x < st) red[threadIdx.x] += red[threadIdx.x + st];
        __syncthreads();
    }
    if (threadIdx.x == 0) xc[bc] = red[0] * (1.0f / LL);
}

// ---------------- Kernel B: channel-attention MLP ----------------
__global__ __launch_bounds__(128) void k_ca(const float* __restrict__ xc,
                     const float* __restrict__ w1, const float* __restrict__ b1,
                     const float* __restrict__ w2, const float* __restrict__ b2,
                     float* __restrict__ ca){
    int b = blockIdx.x;
    int t = threadIdx.x;
    __shared__ float hid[CC/16];
    if (t < CC/16){
        float a = b1[t];
        for (int d = 0; d < CC; d++) a += w1[t*CC + d] * xc[b*CC + d];
        hid[t] = geluf(a);
    }
    __syncthreads();
    if (t < CC){
        float a = b2[t];
        #pragma unroll
        for (int i = 0; i < CC/16; i++) a += w2[t*(CC/16) + i] * hid[i];
        ca[b*CC + t] = sigmoidf(a);
    }
}

// ---------------- Kernel C: depthwise 9x9 conv + bias, scaled by ca ----------------
__global__ __launch_bounds__(256) void k_conv(const float* __restrict__ x, const float* __restrict__ w,
                       const float* __restrict__ bias, const float* __restrict__ ca,
                       float* __restrict__ x1){
    int gid = blockIdx.x * 256 + threadIdx.x; // B*C*L
    int l = gid & (LL-1); int bc = gid >> 12;
    int c = bc % CC; int b = bc / CC;
    int h = l >> 6, wq = l & 63;
    const float* xp = x + (size_t)bc * LL;
    const float* wp = w + c * 81;
    float acc = 0.f;
    #pragma unroll
    for (int ky = 0; ky < 9; ky++){
        int yy = h + ky - 4;
        if (yy < 0 || yy >= HH) continue;
        #pragma unroll
        for (int kx = 0; kx < 9; kx++){
            int xx = wq + kx - 4;
            if (xx < 0 || xx >= WW) continue;
            acc += xp[yy*WW + xx] * wp[ky*9 + kx];
        }
    }
    x1[gid] = (acc + bias[c]) * ca[b*CC + c];
}

// ---------------- Kernel D: rpe resize 7x7 -> 64x64 (b-independent) ----------------
__global__ __launch_bounds__(256) void k_rpe(const float* __restrict__ t, float* __restrict__ out){
    int gid = blockIdx.x * 256 + threadIdx.x; // C*L
    int l = gid & (LL-1); int c = gid >> 12;
    int h = l >> 6, w = l & 63;
    float sy = fmaxf((h + 0.5f) * (7.0f/64.0f) - 0.5f, 0.f);
    float sx = fmaxf((w + 0.5f) * (7.0f/64.0f) - 0.5f, 0.f);
    int y0 = (int)floorf(sy); int x0 = (int)floorf(sx);
    float wy = sy - (float)y0, wx = sx - (float)x0;
    int y1 = min(y0 + 1, 6), x1i = min(x0 + 1, 6);
    const float* tp = t + c * 49;
    float r0 = tp[y0*7 + x0] * (1.f - wy) + tp[y1*7 + x0] * wy;
    float r1 = tp[y0*7 + x1i] * (1.f - wy) + tp[y1*7 + x1i] * wy;
    out[gid] = r0 * (1.f - wx) + r1 * wx;
}

// ---------------- Kernel E: LayerNorm(C) + GELU + 1x1 conv, tiled ----------------
__global__ __launch_bounds__(256) void k_off(const float* __restrict__ x1,
                      const float* __restrict__ g, const float* __restrict__ bta,
                      const float* __restrict__ w2,
                      float* __restrict__ posy, float* __restrict__ posx, float* __restrict__ path){
    int blk = blockIdx.x;            // b*64 + ltile
    int ltile = blk & 63; int b = blk >> 6;
    int lane = threadIdx.x & 63;
    int wg = threadIdx.x >> 6;       // 0..3
    int l = ltile * 64 + lane;
    const float* p = x1 + (size_t)b * CC * LL + l;
    float v[24];
    float s = 0.f, ss = 0.f;
    #pragma unroll
    for (int j = 0; j < 24; j++){
        float t = p[(size_t)(wg*24 + j) * LL];
        v[j] = t; s += t; ss += t*t;
    }
    __shared__ float ls[4][64], lss[4][64];
    ls[wg][lane] = s; lss[wg][lane] = ss;
    __syncthreads();
    s  = ls[0][lane]  + ls[1][lane]  + ls[2][lane]  + ls[3][lane];
    ss = lss[0][lane] + lss[1][lane] + lss[2][lane] + lss[3][lane];
    float m = s * (1.0f/CC);
    float rstd = rsqrtf(ss*(1.0f/CC) - m*m + 1e-5f);
    float a0 = 0.f, a1 = 0.f, a2 = 0.f;
    #pragma unroll
    for (int j = 0; j < 24; j++){
        int c = wg*24 + j;
        float xn = (v[j]-m)*rstd*g[c] + bta[c];
        float xg = geluf(xn);
        a0 = fmaf(w2[c],      xg, a0);
        a1 = fmaf(w2[CC+c],   xg, a1);
        a2 = fmaf(w2[2*CC+c], xg, a2);
    }
    __shared__ float la[3][4][64];
    la[0][wg][lane] = a0; la[1][wg][lane] = a1; la[2][wg][lane] = a2;
    __syncthreads();
    if (wg < 3){
        float a = la[wg][0][lane] + la[wg][1][lane] + la[wg][2][lane] + la[wg][3][lane];
        int h = l >> 6, w = l & 63;
        if (wg == 0)      posy[b*LL + l] = tanhf(a)*(1.0f/63.0f) + ((2*h+1)*(1.0f/63.0f) - 1.0f);
        else if (wg == 1) posx[b*LL + l] = tanhf(a)*(1.0f/63.0f) + ((2*w+1)*(1.0f/63.0f) - 1.0f);
        else              path[b*LL + l] = tanhf(a) + ((l + 0.5f)*(2.0f/4095.0f) - 1.0f);
    }
}

// ---------------- Kernel F: hybrid register/shuffle/LDS stable bitonic argsort ----------------
typedef unsigned long long u64s;
__device__ __forceinline__ u64s shflx64(u64s x, int m){
    int lo = __shfl_xor((int)(unsigned)x, m);
    int hi = __shfl_xor((int)(unsigned)(x >> 32), m);
    return ((u64s)(unsigned)hi << 32) | (unsigned)lo;
}
__device__ __forceinline__ void cex(u64s& a, u64s& b, bool up){
    u64s mn = a < b ? a : b;
    u64s mx = a < b ? b : a;
    a = up ? mn : mx;
    b = up ? mx : mn;
}
__global__ __launch_bounds__(1024) void k_sort(const float* __restrict__ path,
                                               int* __restrict__ idx, int* __restrict__ inv){
    int b = blockIdx.x;
    int t = threadIdx.x;
    __shared__ u64s lds[LL];
    u64s v[4];
    #pragma unroll
    for (int r = 0; r < 4; r++){
        int e = t*4 + r;
        unsigned u = __float_as_uint(path[b*LL + e]);
        u ^= (u >> 31) ? 0xFFFFFFFFu : 0x80000000u;   // monotonic float->uint
        v[r] = ((u64s)u << 32) | (unsigned)e;
    }
    for (int kk = 2; kk <= LL; kk <<= 1){
        for (int j = kk >> 1; j > 0; j >>= 1){
            if (j >= 256){
                __syncthreads();
                #pragma unroll
                for (int r = 0; r < 4; r++) lds[t*4 + r] = v[r];
                __syncthreads();
                #pragma unroll
                for (int r = 0; r < 4; r++){
                    int e = t*4 + r;
                    u64s pv = lds[e ^ j];
                    bool up    = ((e & kk) == 0);
                    bool lower = ((e & j) == 0);
                    u64s mn = v[r] < pv ? v[r] : pv;
                    u64s mx = v[r] < pv ? pv : v[r];
                    v[r] = (up == lower) ? mn : mx;
                }
            } else if (j >= 4){
                int m = j >> 2;
                #pragma unroll
                for (int r = 0; r < 4; r++){
                    u64s pv = shflx64(v[r], m);
                    bool up    = (((t*4 + r) & kk) == 0);
                    bool lower = ((t & m) == 0);
                    u64s mn = v[r] < pv ? v[r] : pv;
                    u64s mx = v[r] < pv ? pv : v[r];
                    v[r] = (up == lower) ? mn : mx;
                }
            } else if (j == 2){
                bool up = (((t*4) & kk) == 0);
                cex(v[0], v[2], up);
                cex(v[1], v[3], up);
            } else { // j == 1
                if (kk == 2){
                    cex(v[0], v[1], true);
                    cex(v[2], v[3], false);
                } else {
                    bool up = (((t*4) & kk) == 0);
                    cex(v[0], v[1], up);
                    cex(v[2], v[3], up);
                }
            }
        }
    }
    #pragma unroll
    for (int r = 0; r < 4; r++){
        int e = t*4 + r;
        int id = (int)(unsigned)(v[r] & 0xFFFFFFFFu);
        idx[b*LL + e] = id;
        inv[b*LL + id] = e;
    }
}

// ---------------- bilinear sample, zero padding ----------------
__device__ __forceinline__ float bilin0(const float* __restrict__ img, float gx, float gy){
    float fx = (gx + 1.f) * 31.5f;   // (W-1)/2 = 31.5
    float fy = (gy + 1.f) * 31.5f;
    float x0f = floorf(fx), y0f = floorf(fy);
    float wx = fx - x0f, wy = fy - y0f;
    int x0 = (int)x0f, y0 = (int)y0f;
    float acc = 0.f;
    bool vx0 = (x0 >= 0) & (x0 < WW), vx1 = (x0+1 >= 0) & (x0+1 < WW);
    bool vy0 = (y0 >= 0) & (y0 < HH), vy1 = (y0+1 >= 0) & (y0+1 < HH);
    if (vy0 & vx0) acc += img[y0*WW + x0]       * (1.f-wx) * (1.f-wy);
    if (vy0 & vx1) acc += img[y0*WW + x0+1]     * wx       * (1.f-wy);
    if (vy1 & vx0) acc += img[(y0+1)*WW + x0]   * (1.f-wx) * wy;
    if (vy1 & vx1) acc += img[(y0+1)*WW + x0+1] * wx       * wy;
    return acc;
}

// ---------------- Kernel S: x grid-sample + rpe grid-sample -> xd ----------------
__global__ __launch_bounds__(256) void k_sample(const float* __restrict__ x, const float* __restrict__ rpe,
                         const float* __restrict__ posy, const float* __restrict__ posx,
                         float* __restrict__ xd){
    int gid = blockIdx.x * 256 + threadIdx.x; // B*C*L
    int l = gid & (LL-1); int bc = gid >> 12;
    int b = bc / CC; int c = bc % CC;
    float gy = posy[b*LL + l], gx = posx[b*LL + l];
    float v = bilin0(x + (size_t)bc * LL, gx, gy);
    int h = l >> 6, w = l & 63;
    float ky = h * (128.0f/3969.0f) - 1.0f;  // linspace(0,64,64)/63*2-1
    float kx = w * (128.0f/3969.0f) - 1.0f;
    float v2 = bilin0(rpe + (size_t)c * LL, (kx - gx) * 0.5f, (ky - gy) * 0.5f);
    xd[gid] = v + v2;
}

// ---------------- Kernel G: projection, 16 l's per wave, channel-quarter split ----------------
// lane = l_local*4 + part; lane loads v[24] for channels [24*part, 24*part+24),
// computes partial acc[38], 2-step shfl_xor butterfly -> full sums on all lanes.
// B/C: part p stores float4 elements [4p,4p+4) -> wave stores are contiguous.
// dt epilogue: 24 channels per lane. Grid = B*K*256 single-wave blocks (3/SIMD).
__global__ __launch_bounds__(64) void k_proj(const float* __restrict__ x, const float* __restrict__ xd,
    const int* __restrict__ indices, const float* __restrict__ xpw, const float* __restrict__ dtw,
    const float* __restrict__ dtb, float* __restrict__ u2, float* __restrict__ dt,
    float* __restrict__ Bst, float* __restrict__ Cst){
    int blk = blockIdx.x;          // B*K*256 blocks
    int ltile = blk & 255; int bk = blk >> 8;
    int k = bk % KK; int b = bk / KK;
    int lane = threadIdx.x;
    int ll = lane >> 2;            // 0..15
    int part = lane & 3;           // 0..3
    int l = ltile * 16 + ll;
    int srcl = (k == 0) ? l : (k == 1 ? (LL-1-l) : indices[b*LL + l]);
    const float* xp = (k == 2 ? xd : x) + (size_t)b * CC * LL + srcl;
    const float* __restrict__ Wk = xpw + k*38*CC;

    // 24 independent loads, all in flight
    float v[24];
    #pragma unroll
    for (int j = 0; j < 24; j++) v[j] = xp[(size_t)(part*24 + j) * LL];

    float acc[38];
    #pragma unroll
    for (int i = 0; i < 38; i++) acc[i] = 0.f;
    #pragma unroll
    for (int j = 0; j < 24; j++){
        int d = part*24 + j;
        #pragma unroll
        for (int i = 0; i < 38; i++) acc[i] = fmaf(Wk[i*CC + d], v[j], acc[i]);
    }
    // butterfly over the 4 part-lanes -> all lanes hold full sums
    #pragma unroll
    for (int i = 0; i < 38; i++){
        acc[i] += __shfl_xor(acc[i], 1);
        acc[i] += __shfl_xor(acc[i], 2);
    }

    size_t base = ((size_t)bk * LL + l) * NN;
    {
        float4 o;
        o.x = acc[RR + 4*part + 0]; o.y = acc[RR + 4*part + 1];
        o.z = acc[RR + 4*part + 2]; o.w = acc[RR + 4*part + 3];
        *(float4*)(Bst + base + 4*part) = o;
        float4 p2;
        p2.x = acc[RR+NN + 4*part + 0]; p2.y = acc[RR+NN + 4*part + 1];
        p2.z = acc[RR+NN + 4*part + 2]; p2.w = acc[RR+NN + 4*part + 3];
        *(float4*)(Cst + base + 4*part) = p2;
    }
    if (k == 2){
        float* up = u2 + (size_t)b * CC * LL + l;
        #pragma unroll
        for (int j = 0; j < 24; j++) up[(size_t)(part*24 + j) * LL] = v[j];
    }
    const float* __restrict__ Dw = dtw + k*CC*RR;
    const float* __restrict__ Db = dtb + k*CC;
    float* dtp = dt + (size_t)bk * CC * LL + l;
    #pragma unroll 4
    for (int j = 0; j < 24; j++){
        int d = part*24 + j;
        float sdt = Db[d];
        #pragma unroll
        for (int r = 0; r < RR; r++) sdt = fmaf(acc[r], Dw[d*RR + r], sdt);
        dtp[(size_t)d * LL] = softplusf(sdt);
    }
}

// ---------------- Kernel H: merged selective scan ----------------
#define SEG 128        // segments
#define TL 32          // steps per segment
#define SROW 17        // padded row stride for sA/sB (words)
#define DROW 36        // padded row stride for sdt (words), 16B-aligned
template<int KIND>
__device__ __forceinline__ void scan_body(int b, int d, const float* __restrict__ usrc,
    const float* __restrict__ dt, const float* __restrict__ Bst, const float* __restrict__ Cst,
    const float* __restrict__ Alog, const float* __restrict__ Ds, float* __restrict__ ys,
    float* sA, float* sB, float* sdt){
    int bk = b * KK + KIND;
    int tid = threadIdx.x;
    int ng = tid & 3;          // n = 4*ng + j
    int seg = tid >> 2;        // 0..127
    int t0 = seg * TL;

    const float4 A4 = *(const float4*)(Alog + (KIND*CC + d)*NN + 4*ng);
    float A[4] = { -__expf(A4.x), -__expf(A4.y), -__expf(A4.z), -__expf(A4.w) };
    float Dv = Ds[KIND*CC + d];

    const float* dtp = dt + ((size_t)bk * CC + d) * LL + t0;
    const float* ub = (KIND == 1)
        ? usrc + ((size_t)b*CC + d) * LL + (LL-4-t0)
        : usrc + ((size_t)b*CC + d) * LL + t0;
    const float* Bp = Bst + ((size_t)bk * LL + t0) * NN + 4*ng;
    const float* Cp = Cst + ((size_t)bk * LL + t0) * NN + 4*ng;
    float* yp = ys + ((size_t)bk * CC + d) * LL + t0;

    // Phase 1: local segment scan from h=0; stage dt (scan order) into LDS
    float Ap[4] = {1.f,1.f,1.f,1.f}, h[4] = {0.f,0.f,0.f,0.f};
    for (int t = 0; t < TL; t += 4){
        float4 dq = *(const float4*)(dtp + t);
        float4 uq = (KIND == 1) ? *(const float4*)(ub - t) : *(const float4*)(ub + t);
        float dd[4] = {dq.x, dq.y, dq.z, dq.w};
        float uu[4];
        if (KIND == 1){ uu[0]=uq.w; uu[1]=uq.z; uu[2]=uq.y; uu[3]=uq.x; }
        else          { uu[0]=uq.x; uu[1]=uq.y; uu[2]=uq.z; uu[3]=uq.w; }
        if (ng == 0) *(float4*)(sdt + seg*DROW + t) = dq;
        #pragma unroll
        for (int i = 0; i < 4; i++){
            float4 Bq = *(const float4*)(Bp + (t+i)*NN);
            float du = dd[i] * uu[i];
            float bb[4] = {Bq.x, Bq.y, Bq.z, Bq.w};
            #pragma unroll
            for (int j = 0; j < 4; j++){
                float a = __expf(dd[i] * A[j]);
                Ap[j] *= a;
                h[j] = fmaf(a, h[j], du * bb[j]);
            }
        }
    }

    // Phase 2: per-wave shuffle scan over 128 segments (exclusive carries)
    #pragma unroll
    for (int j = 0; j < 4; j++){
        sA[seg*SROW + 4*ng + j] = Ap[j];
        sB[seg*SROW + 4*ng + j] = h[j];
    }
    __syncthreads();
    {
        int wv = tid >> 6;         // 0..7
        int lane = tid & 63;
        #pragma unroll
        for (int nn = 0; nn < 2; nn++){
            int n = 2*wv + nn;
            float a1 = sA[(2*lane)*SROW + n],   b1 = sB[(2*lane)*SROW + n];
            float a2 = sA[(2*lane+1)*SROW + n], b2 = sB[(2*lane+1)*SROW + n];
            float ca = a1 * a2;
            float cb = fmaf(a2, b1, b2);
            #pragma unroll
            for (int off = 1; off < 64; off <<= 1){
                float ta = __shfl_up(ca, off);
                float tb = __shfl_up(cb, off);
                if (lane >= off){
                    cb = fmaf(ca, tb, cb);
                    ca *= ta;
                }
            }
            float cb_prev = __shfl_up(cb, 1);
            if (lane == 0) cb_prev = 0.f;
            sA[(2*lane)*SROW + n]   = cb_prev;
            sA[(2*lane+1)*SROW + n] = fmaf(a1, cb_prev, b1);
        }
    }
    __syncthreads();
    float hc[4];
    #pragma unroll
    for (int j = 0; j < 4; j++) hc[j] = sA[seg*SROW + 4*ng + j];

    // Phase 3: replay with carry-in; dt from LDS, u from global
    for (int t = 0; t < TL; t += 4){
        float4 dq = *(const float4*)(sdt + seg*DROW + t);
        float4 uq = (KIND == 1) ? *(const float4*)(ub - t) : *(const float4*)(ub + t);
        float dd[4] = {dq.x, dq.y, dq.z, dq.w};
        float uu[4];
        if (KIND == 1){ uu[0]=uq.w; uu[1]=uq.z; uu[2]=uq.y; uu[3]=uq.x; }
        else          { uu[0]=uq.x; uu[1]=uq.y; uu[2]=uq.z; uu[3]=uq.w; }
        float yo[4];
        #pragma unroll
        for (int i = 0; i < 4; i++){
            float4 Bq = *(const float4*)(Bp + (t+i)*NN);
            float4 Cq = *(const float4*)(Cp + (t+i)*NN);
            float du = dd[i] * uu[i];
            float bb[4] = {Bq.x, Bq.y, Bq.z, Bq.w};
            float cc[4] = {Cq.x, Cq.y, Cq.z, Cq.w};
            float p = 0.f;
            #pragma unroll
            for (int j = 0; j < 4; j++){
                float a = __expf(dd[i] * A[j]);
                hc[j] = fmaf(a, hc[j], du * bb[j]);
                p = fmaf(hc[j], cc[j], p);
            }
            p += __shfl_xor(p, 1);
            p += __shfl_xor(p, 2);
            yo[i] = fmaf(uu[i], Dv, p);
        }
        if (ng == 0){
            float4 o; o.x = yo[0]; o.y = yo[1]; o.z = yo[2]; o.w = yo[3];
            *(float4*)(yp + t) = o;
        }
    }
}

__global__ __launch_bounds__(512) void k_scan_all(const float* __restrict__ x, const float* __restrict__ u2,
    const float* __restrict__ dt, const float* __restrict__ Bst, const float* __restrict__ Cst,
    const float* __restrict__ Alog, const float* __restrict__ Ds, float* __restrict__ ys){
    __shared__ float sA[SEG*SROW];
    __shared__ float sB[SEG*SROW];
    __shared__ float sdt[SEG*DROW];
    int blk = blockIdx.x;            // KK*BB*CC
    int k = blk / (BB*CC);
    int r = blk % (BB*CC);
    int d = r % CC; int b = r / CC;
    if (k == 0)      scan_body<0>(b, d, x,  dt, Bst, Cst, Alog, Ds, ys, sA, sB, sdt);
    else if (k == 1) scan_body<1>(b, d, x,  dt, Bst, Cst, Alog, Ds, ys, sA, sB, sdt);
    else             scan_body<2>(b, d, u2, dt, Bst, Cst, Alog, Ds, ys, sA, sB, sdt);
}

// ---------------- Kernel I: combine 3 paths + transpose to (B,L,C) ----------------
__global__ __launch_bounds__(256) void k_comb(const float* __restrict__ ys, const int* __restrict__ inv,
                                              float* __restrict__ out){
    int tile = blockIdx.x & 63; int b = blockIdx.x >> 6;
    int l0 = tile * 64;
    __shared__ float t0[CC * 65];
    __shared__ int invs[64];
    if (threadIdx.x < 64) invs[threadIdx.x] = inv[b*LL + l0 + threadIdx.x];
    __syncthreads();
    const float* y0p = ys + (size_t)(b*KK + 0) * CC * LL;
    const float* y1p = ys + (size_t)(b*KK + 1) * CC * LL;
    const float* y2p = ys + (size_t)(b*KK + 2) * CC * LL;
    for (int it = 0; it < 24; it++){
        int e = it * 256 + threadIdx.x;
        int li = e & 63; int c = e >> 6;
        int l = l0 + li;
        float v = y0p[(size_t)c*LL + l] + y1p[(size_t)c*LL + (LL-1-l)] + y2p[(size_t)c*LL + invs[li]];
        t0[c*65 + li] = v * (1.0f/3.0f);
    }
    __syncthreads();
    for (int it = 0; it < 24; it++){
        int e = it * 256 + threadIdx.x;
        int c = e % CC; int li = e / CC;
        out[((size_t)b*LL + l0 + li) * CC + c] = t0[c*65 + li];
    }
}

extern "C" void kernel_launch(void* const* d_in, const int* in_sizes, int n_in,
                              void* d_out, int out_size, void* d_ws, size_t ws_size,
                              hipStream_t stream){
    const float* x    = (const float*)d_in[0];
    const float* xpw  = (const float*)d_in[1];
    const float* dtw  = (const float*)d_in[2];
    const float* dtb  = (const float*)d_in[3];
    const float* Alog = (const float*)d_in[4];
    const float* Ds   = (const float*)d_in[5];
    const float* c1w  = (const float*)d_in[6];
    const float* c1b  = (const float*)d_in[7];
    const float* ca1w = (const float*)d_in[8];
    const float* ca1b = (const float*)d_in[9];
    const float* ca2w = (const float*)d_in[10];
    const float* ca2b = (const float*)d_in[11];
    const float* lng  = (const float*)d_in[12];
    const float* lnb  = (const float*)d_in[13];
    const float* c2w  = (const float*)d_in[14];
    const float* rpet = (const float*)d_in[15];
    float* out = (float*)d_out;

    float* ws   = (float*)d_ws;
    float* xc   = ws;                      // 384
    float* ca   = xc + 384;                // 384
    float* x1   = ca + 384;                // B*C*L = 1572864
    float* rpe  = x1 + (size_t)BB*CC*LL;   // C*L = 393216
    float* posy = rpe + (size_t)CC*LL;     // B*L
    float* posx = posy + (size_t)BB*LL;
    float* path = posx + (size_t)BB*LL;
    float* xd   = path + (size_t)BB*LL;    // B*C*L
    int*   idx  = (int*)(xd + (size_t)BB*CC*LL);   // B*L ints
    int*   inv  = idx + (size_t)BB*LL;             // B*L ints
    float* u2   = (float*)(inv + (size_t)BB*LL);   // B*C*L
    float* dtA  = u2 + (size_t)BB*CC*LL;           // B*K*C*L = 4718592
    float* Bst  = dtA + (size_t)BB*KK*CC*LL;       // B*K*L*N = 786432
    float* Cst  = Bst + (size_t)BB*KK*LL*NN;
    float* ysA  = Cst + (size_t)BB*KK*LL*NN;       // B*K*C*L

    k_mean  <<<BB*CC, 256, 0, stream>>>(x, xc);
    k_ca    <<<BB, 128, 0, stream>>>(xc, ca1w, ca1b, ca2w, ca2b, ca);
    k_conv  <<<(BB*CC*LL)/256, 256, 0, stream>>>(x, c1w, c1b, ca, x1);
    k_rpe   <<<(CC*LL)/256, 256, 0, stream>>>(rpet, rpe);
    k_off   <<<BB*64, 256, 0, stream>>>(x1, lng, lnb, c2w, posy, posx, path);
    k_sort  <<<BB, 1024, 0, stream>>>(path, idx, inv);
    k_sample<<<(BB*CC*LL)/256, 256, 0, stream>>>(x, rpe, posy, posx, xd);
    k_proj  <<<BB*KK*256, 64, 0, stream>>>(x, xd, idx, xpw, dtw, dtb, u2, dtA, Bst, Cst);
    k_scan_all<<<KK*BB*CC, 512, 0, stream>>>(x, u2, dtA, Bst, Cst, Alog, Ds, ysA);
    k_comb  <<<BB*64, 256, 0, stream>>>(ysA, inv, out);
}

// Round 13
// 354.127 us; speedup vs baseline: 1.0547x; 1.0547x over previous
//
#include <hip/hip_runtime.h>

#define BB 4
#define CC 96
#define HH 64
#define WW 64
#define LL 4096
#define KK 3
#define RR 6
#define NN 16

__device__ __forceinline__ float geluf(float x){
    return 0.5f * x * (1.0f + erff(x * 0.70710678118654752f));
}
__device__ __forceinline__ float softplusf(float x){
    return fmaxf(x, 0.0f) + log1pf(expf(-fabsf(x)));
}
__device__ __forceinline__ float sigmoidf(float x){
    return 1.0f / (1.0f + expf(-x));
}

// ---------------- Kernel A: per-(b,c) spatial mean ----------------
__global__ __launch_bounds__(256) void k_mean(const float* __restrict__ x, float* __restrict__ xc){
    int bc = blockIdx.x; // 0..B*C-1
    const float* p = x + (size_t)bc * LL;
    float s = 0.f;
    for (int i = threadIdx.x; i < LL; i += 256) s += p[i];
    __shared__ float red[256];
    red[threadIdx.x] = s; __syncthreads();
    for (int st = 128; st > 0; st >>= 1){
        if (threadIdx.x < st) red[threadIdx.x] += red[threadIdx.x + st];
        __syncthreads();
    }
    if (threadIdx.x == 0) xc[bc] = red[0] * (1.0f / LL);
}

// ---------------- Kernel B: channel-attention MLP ----------------
__global__ __launch_bounds__(128) void k_ca(const float* __restrict__ xc,
                     const float* __restrict__ w1, const float* __restrict__ b1,
                     const float* __restrict__ w2, const float* __restrict__ b2,
                     float* __restrict__ ca){
    int b = blockIdx.x;
    int t = threadIdx.x;
    __shared__ float hid[CC/16];
    if (t < CC/16){
        float a = b1[t];
        for (int d = 0; d < CC; d++) a += w1[t*CC + d] * xc[b*CC + d];
        hid[t] = geluf(a);
    }
    __syncthreads();
    if (t < CC){
        float a = b2[t];
        #pragma unroll
        for (int i = 0; i < CC/16; i++) a += w2[t*(CC/16) + i] * hid[i];
        ca[b*CC + t] = sigmoidf(a);
    }
}

// ---------------- Kernel C: depthwise 9x9 conv + bias, scaled by ca ----------------
__global__ __launch_bounds__(256) void k_conv(const float* __restrict__ x, const float* __restrict__ w,
                       const float* __restrict__ bias, const float* __restrict__ ca,
                       float* __restrict__ x1){
    int gid = blockIdx.x * 256 + threadIdx.x; // B*C*L
    int l = gid & (LL-1); int bc = gid >> 12;
    int c = bc % CC; int b = bc / CC;
    int h = l >> 6, wq = l & 63;
    const float* xp = x + (size_t)bc * LL;
    const float* wp = w + c * 81;
    float acc = 0.f;
    #pragma unroll
    for (int ky = 0; ky < 9; ky++){
        int yy = h + ky - 4;
        if (yy < 0 || yy >= HH) continue;
        #pragma unroll
        for (int kx = 0; kx < 9; kx++){
            int xx = wq + kx - 4;
            if (xx < 0 || xx >= WW) continue;
            acc += xp[yy*WW + xx] * wp[ky*9 + kx];
        }
    }
    x1[gid] = (acc + bias[c]) * ca[b*CC + c];
}

// ---------------- Kernel D: rpe resize 7x7 -> 64x64 (b-independent) ----------------
__global__ __launch_bounds__(256) void k_rpe(const float* __restrict__ t, float* __restrict__ out){
    int gid = blockIdx.x * 256 + threadIdx.x; // C*L
    int l = gid & (LL-1); int c = gid >> 12;
    int h = l >> 6, w = l & 63;
    float sy = fmaxf((h + 0.5f) * (7.0f/64.0f) - 0.5f, 0.f);
    float sx = fmaxf((w + 0.5f) * (7.0f/64.0f) - 0.5f, 0.f);
    int y0 = (int)floorf(sy); int x0 = (int)floorf(sx);
    float wy = sy - (float)y0, wx = sx - (float)x0;
    int y1 = min(y0 + 1, 6), x1i = min(x0 + 1, 6);
    const float* tp = t + c * 49;
    float r0 = tp[y0*7 + x0] * (1.f - wy) + tp[y1*7 + x0] * wy;
    float r1 = tp[y0*7 + x1i] * (1.f - wy) + tp[y1*7 + x1i] * wy;
    out[gid] = r0 * (1.f - wx) + r1 * wx;
}

// ---------------- Kernel E: LayerNorm(C) + GELU + 1x1 conv, tiled ----------------
__global__ __launch_bounds__(256) void k_off(const float* __restrict__ x1,
                      const float* __restrict__ g, const float* __restrict__ bta,
                      const float* __restrict__ w2,
                      float* __restrict__ posy, float* __restrict__ posx, float* __restrict__ path){
    int blk = blockIdx.x;            // b*64 + ltile
    int ltile = blk & 63; int b = blk >> 6;
    int lane = threadIdx.x & 63;
    int wg = threadIdx.x >> 6;       // 0..3
    int l = ltile * 64 + lane;
    const float* p = x1 + (size_t)b * CC * LL + l;
    float v[24];
    float s = 0.f, ss = 0.f;
    #pragma unroll
    for (int j = 0; j < 24; j++){
        float t = p[(size_t)(wg*24 + j) * LL];
        v[j] = t; s += t; ss += t*t;
    }
    __shared__ float ls[4][64], lss[4][64];
    ls[wg][lane] = s; lss[wg][lane] = ss;
    __syncthreads();
    s  = ls[0][lane]  + ls[1][lane]  + ls[2][lane]  + ls[3][lane];
    ss = lss[0][lane] + lss[1][lane] + lss[2][lane] + lss[3][lane];
    float m = s * (1.0f/CC);
    float rstd = rsqrtf(ss*(1.0f/CC) - m*m + 1e-5f);
    float a0 = 0.f, a1 = 0.f, a2 = 0.f;
    #pragma unroll
    for (int j = 0; j < 24; j++){
        int c = wg*24 + j;
        float xn = (v[j]-m)*rstd*g[c] + bta[c];
        float xg = geluf(xn);
        a0 = fmaf(w2[c],      xg, a0);
        a1 = fmaf(w2[CC+c],   xg, a1);
        a2 = fmaf(w2[2*CC+c], xg, a2);
    }
    __shared__ float la[3][4][64];
    la[0][wg][lane] = a0; la[1][wg][lane] = a1; la[2][wg][lane] = a2;
    __syncthreads();
    if (wg < 3){
        float a = la[wg][0][lane] + la[wg][1][lane] + la[wg][2][lane] + la[wg][3][lane];
        int h = l >> 6, w = l & 63;
        if (wg == 0)      posy[b*LL + l] = tanhf(a)*(1.0f/63.0f) + ((2*h+1)*(1.0f/63.0f) - 1.0f);
        else if (wg == 1) posx[b*LL + l] = tanhf(a)*(1.0f/63.0f) + ((2*w+1)*(1.0f/63.0f) - 1.0f);
        else              path[b*LL + l] = tanhf(a) + ((l + 0.5f)*(2.0f/4095.0f) - 1.0f);
    }
}

// ---------------- Kernel F: hybrid register/shuffle/LDS stable bitonic argsort ----------------
typedef unsigned long long u64s;
__device__ __forceinline__ u64s shflx64(u64s x, int m){
    int lo = __shfl_xor((int)(unsigned)x, m);
    int hi = __shfl_xor((int)(unsigned)(x >> 32), m);
    return ((u64s)(unsigned)hi << 32) | (unsigned)lo;
}
__device__ __forceinline__ void cex(u64s& a, u64s& b, bool up){
    u64s mn = a < b ? a : b;
    u64s mx = a < b ? b : a;
    a = up ? mn : mx;
    b = up ? mx : mn;
}
__global__ __launch_bounds__(1024) void k_sort(const float* __restrict__ path,
                                               int* __restrict__ idx, int* __restrict__ inv){
    int b = blockIdx.x;
    int t = threadIdx.x;
    __shared__ u64s lds[LL];
    u64s v[4];
    #pragma unroll
    for (int r = 0; r < 4; r++){
        int e = t*4 + r;
        unsigned u = __float_as_uint(path[b*LL + e]);
        u ^= (u >> 31) ? 0xFFFFFFFFu : 0x80000000u;   // monotonic float->uint
        v[r] = ((u64s)u << 32) | (unsigned)e;
    }
    for (int kk = 2; kk <= LL; kk <<= 1){
        for (int j = kk >> 1; j > 0; j >>= 1){
            if (j >= 256){
                __syncthreads();
                #pragma unroll
                for (int r = 0; r < 4; r++) lds[t*4 + r] = v[r];
                __syncthreads();
                #pragma unroll
                for (int r = 0; r < 4; r++){
                    int e = t*4 + r;
                    u64s pv = lds[e ^ j];
                    bool up    = ((e & kk) == 0);
                    bool lower = ((e & j) == 0);
                    u64s mn = v[r] < pv ? v[r] : pv;
                    u64s mx = v[r] < pv ? pv : v[r];
                    v[r] = (up == lower) ? mn : mx;
                }
            } else if (j >= 4){
                int m = j >> 2;
                #pragma unroll
                for (int r = 0; r < 4; r++){
                    u64s pv = shflx64(v[r], m);
                    bool up    = (((t*4 + r) & kk) == 0);
                    bool lower = ((t & m) == 0);
                    u64s mn = v[r] < pv ? v[r] : pv;
                    u64s mx = v[r] < pv ? pv : v[r];
                    v[r] = (up == lower) ? mn : mx;
                }
            } else if (j == 2){
                bool up = (((t*4) & kk) == 0);
                cex(v[0], v[2], up);
                cex(v[1], v[3], up);
            } else { // j == 1
                if (kk == 2){
                    cex(v[0], v[1], true);
                    cex(v[2], v[3], false);
                } else {
                    bool up = (((t*4) & kk) == 0);
                    cex(v[0], v[1], up);
                    cex(v[2], v[3], up);
                }
            }
        }
    }
    #pragma unroll
    for (int r = 0; r < 4; r++){
        int e = t*4 + r;
        int id = (int)(unsigned)(v[r] & 0xFFFFFFFFu);
        idx[b*LL + e] = id;
        inv[b*LL + id] = e;
    }
}

// ---------------- bilinear sample, zero padding ----------------
__device__ __forceinline__ float bilin0(const float* __restrict__ img, float gx, float gy){
    float fx = (gx + 1.f) * 31.5f;   // (W-1)/2 = 31.5
    float fy = (gy + 1.f) * 31.5f;
    float x0f = floorf(fx), y0f = floorf(fy);
    float wx = fx - x0f, wy = fy - y0f;
    int x0 = (int)x0f, y0 = (int)y0f;
    float acc = 0.f;
    bool vx0 = (x0 >= 0) & (x0 < WW), vx1 = (x0+1 >= 0) & (x0+1 < WW);
    bool vy0 = (y0 >= 0) & (y0 < HH), vy1 = (y0+1 >= 0) & (y0+1 < HH);
    if (vy0 & vx0) acc += img[y0*WW + x0]       * (1.f-wx) * (1.f-wy);
    if (vy0 & vx1) acc += img[y0*WW + x0+1]     * wx       * (1.f-wy);
    if (vy1 & vx0) acc += img[(y0+1)*WW + x0]   * (1.f-wx) * wy;
    if (vy1 & vx1) acc += img[(y0+1)*WW + x0+1] * wx       * wy;
    return acc;
}

// ---------------- Kernel S: x grid-sample + rpe grid-sample -> xd ----------------
__global__ __launch_bounds__(256) void k_sample(const float* __restrict__ x, const float* __restrict__ rpe,
                         const float* __restrict__ posy, const float* __restrict__ posx,
                         float* __restrict__ xd){
    int gid = blockIdx.x * 256 + threadIdx.x; // B*C*L
    int l = gid & (LL-1); int bc = gid >> 12;
    int b = bc / CC; int c = bc % CC;
    float gy = posy[b*LL + l], gx = posx[b*LL + l];
    float v = bilin0(x + (size_t)bc * LL, gx, gy);
    int h = l >> 6, w = l & 63;
    float ky = h * (128.0f/3969.0f) - 1.0f;  // linspace(0,64,64)/63*2-1
    float kx = w * (128.0f/3969.0f) - 1.0f;
    float v2 = bilin0(rpe + (size_t)c * LL, (kx - gx) * 0.5f, (ky - gy) * 0.5f);
    xd[gid] = v + v2;
}

// ---------------- Kernel G: projection, 3-wave output split + shared v in LDS (R11 known-good) ----------------
// 64 consecutive l's per plane access = full 256B coalescing (R12's 16-l layout
// halved segment width and regressed: WRITE_SIZE 30->55 MB).
__global__ __launch_bounds__(192, 1) void k_proj(const float* __restrict__ x, const float* __restrict__ xd,
    const int* __restrict__ indices, const float* __restrict__ xpw, const float* __restrict__ dtw,
    const float* __restrict__ dtb, float* __restrict__ u2, float* __restrict__ dt,
    float* __restrict__ Bst, float* __restrict__ Cst){
    int blk = blockIdx.x;          // B*K*64 blocks
    int ltile = blk & 63; int bk = blk >> 6;
    int k = bk % KK; int b = bk / KK;
    int lane = threadIdx.x & 63;
    int w = threadIdx.x >> 6;      // 0..2
    const float* __restrict__ Wk = xpw + k*38*CC;
    int l = ltile * 64 + lane;
    int srcl = (k == 0) ? l : (k == 1 ? (LL-1-l) : indices[b*LL + l]);
    const float* xp = (k == 2 ? xd : x) + (size_t)b * CC * LL + srcl;

    __shared__ float vsh[CC*64];   // 24 KB
    #pragma unroll
    for (int j = 0; j < 32; j++){
        int d = w*32 + j;
        vsh[d*64 + lane] = xp[(size_t)d * LL];
    }
    __syncthreads();

    if (w == 0){
        float acc[RR];
        #pragma unroll
        for (int i = 0; i < RR; i++) acc[i] = 0.f;
        for (int d = 0; d < CC; d++){
            float vv = vsh[d*64 + lane];
            #pragma unroll
            for (int i = 0; i < RR; i++) acc[i] = fmaf(Wk[i*CC + d], vv, acc[i]);
        }
        const float* __restrict__ Dw = dtw + k*CC*RR;
        const float* __restrict__ Db = dtb + k*CC;
        float* dtp = dt + (size_t)bk * CC * LL + l;
        #pragma unroll 8
        for (int d = 0; d < CC; d++){
            float sdt = Db[d];
            #pragma unroll
            for (int r = 0; r < RR; r++) sdt = fmaf(acc[r], Dw[d*RR + r], sdt);
            dtp[(size_t)d * LL] = softplusf(sdt);
        }
    } else if (w == 1){
        float acc[NN];
        #pragma unroll
        for (int i = 0; i < NN; i++) acc[i] = 0.f;
        for (int d = 0; d < CC; d++){
            float vv = vsh[d*64 + lane];
            #pragma unroll
            for (int i = 0; i < NN; i++) acc[i] = fmaf(Wk[(RR + i)*CC + d], vv, acc[i]);
        }
        size_t base = ((size_t)bk * LL + l) * NN;
        #pragma unroll
        for (int q = 0; q < 4; q++){
            float4 o; o.x = acc[q*4]; o.y = acc[q*4+1]; o.z = acc[q*4+2]; o.w = acc[q*4+3];
            *(float4*)(Bst + base + q*4) = o;
        }
    } else {
        float acc[NN];
        #pragma unroll
        for (int i = 0; i < NN; i++) acc[i] = 0.f;
        for (int d = 0; d < CC; d++){
            float vv = vsh[d*64 + lane];
            #pragma unroll
            for (int i = 0; i < NN; i++) acc[i] = fmaf(Wk[(RR + NN + i)*CC + d], vv, acc[i]);
        }
        size_t base = ((size_t)bk * LL + l) * NN;
        #pragma unroll
        for (int q = 0; q < 4; q++){
            float4 o; o.x = acc[q*4]; o.y = acc[q*4+1]; o.z = acc[q*4+2]; o.w = acc[q*4+3];
            *(float4*)(Cst + base + q*4) = o;
        }
        if (k == 2){
            float* up = u2 + (size_t)b * CC * LL + l;
            #pragma unroll 8
            for (int d = 0; d < CC; d++) up[(size_t)d * LL] = vsh[d*64 + lane];
        }
    }
}

// ---------------- Kernel H: merged selective scan, 2 n-chains/thread ----------------
// Block = one (bk,d), 512 thr = 64 segments x 8 n-groups; segment = 64 steps.
// 2 chains/thread halves register arrays (VGPR ~108 -> target <88) -> 6 waves/SIMD
// -> 3 blocks/CU -> dispatch rounds 2.25 -> 1.5. No dt LDS cache (re-read from
// global). Phase 2: 1 segment per lane, clean 64-wide shuffle scan per 2 chains.
#define SEG 64         // segments
#define TL 64          // steps per segment
#define SROW 17        // padded row stride for sA/sB (words)
template<int KIND>
__device__ __forceinline__ void scan_body(int b, int d, const float* __restrict__ usrc,
    const float* __restrict__ dt, const float* __restrict__ Bst, const float* __restrict__ Cst,
    const float* __restrict__ Alog, const float* __restrict__ Ds, float* __restrict__ ys,
    float* sA, float* sB){
    int bk = b * KK + KIND;
    int tid = threadIdx.x;
    int ng = tid & 7;          // n = 2*ng + j, j in {0,1}
    int seg = tid >> 3;        // 0..63
    int t0 = seg * TL;

    const float2 A2 = *(const float2*)(Alog + (KIND*CC + d)*NN + 2*ng);
    float A[2] = { -__expf(A2.x), -__expf(A2.y) };
    float Dv = Ds[KIND*CC + d];

    const float* dtp = dt + ((size_t)bk * CC + d) * LL + t0;
    const float* ub = (KIND == 1)
        ? usrc + ((size_t)b*CC + d) * LL + (LL-4-t0)
        : usrc + ((size_t)b*CC + d) * LL + t0;
    const float* Bp = Bst + ((size_t)bk * LL + t0) * NN + 2*ng;
    const float* Cp = Cst + ((size_t)bk * LL + t0) * NN + 2*ng;
    float* yp = ys + ((size_t)bk * CC + d) * LL + t0;

    // Phase 1: local segment scan from h=0
    float Ap[2] = {1.f,1.f}, h[2] = {0.f,0.f};
    for (int t = 0; t < TL; t += 4){
        float4 dq = *(const float4*)(dtp + t);
        float4 uq = (KIND == 1) ? *(const float4*)(ub - t) : *(const float4*)(ub + t);
        float dd[4] = {dq.x, dq.y, dq.z, dq.w};
        float uu[4];
        if (KIND == 1){ uu[0]=uq.w; uu[1]=uq.z; uu[2]=uq.y; uu[3]=uq.x; }
        else          { uu[0]=uq.x; uu[1]=uq.y; uu[2]=uq.z; uu[3]=uq.w; }
        #pragma unroll
        for (int i = 0; i < 4; i++){
            float2 Bq = *(const float2*)(Bp + (t+i)*NN);
            float du = dd[i] * uu[i];
            float a0 = __expf(dd[i] * A[0]);
            float a1 = __expf(dd[i] * A[1]);
            Ap[0] *= a0; Ap[1] *= a1;
            h[0] = fmaf(a0, h[0], du * Bq.x);
            h[1] = fmaf(a1, h[1], du * Bq.y);
        }
    }

    // Phase 2: 64-wide shuffle scan over segments (exclusive carries), 2 chains/wave-pass
    #pragma unroll
    for (int j = 0; j < 2; j++){
        sA[seg*SROW + 2*ng + j] = Ap[j];
        sB[seg*SROW + 2*ng + j] = h[j];
    }
    __syncthreads();
    {
        int wv = tid >> 6;         // 0..7
        int lane = tid & 63;       // = segment index
        #pragma unroll
        for (int nn = 0; nn < 2; nn++){
            int n = 2*wv + nn;
            float ca = sA[lane*SROW + n];
            float cb = sB[lane*SROW + n];
            #pragma unroll
            for (int off = 1; off < 64; off <<= 1){
                float ta = __shfl_up(ca, off);
                float tb = __shfl_up(cb, off);
                if (lane >= off){
                    cb = fmaf(ca, tb, cb);
                    ca *= ta;
                }
            }
            float cb_prev = __shfl_up(cb, 1);
            if (lane == 0) cb_prev = 0.f;
            sA[lane*SROW + n] = cb_prev;   // exclusive carry (columns wave-private)
        }
    }
    __syncthreads();
    float hc[2];
    #pragma unroll
    for (int j = 0; j < 2; j++) hc[j] = sA[seg*SROW + 2*ng + j];

    // Phase 3: replay with carry-in; dt/u from global, emit y float4 from ng==0
    for (int t = 0; t < TL; t += 4){
        float4 dq = *(const float4*)(dtp + t);
        float4 uq = (KIND == 1) ? *(const float4*)(ub - t) : *(const float4*)(ub + t);
        float dd[4] = {dq.x, dq.y, dq.z, dq.w};
        float uu[4];
        if (KIND == 1){ uu[0]=uq.w; uu[1]=uq.z; uu[2]=uq.y; uu[3]=uq.x; }
        else          { uu[0]=uq.x; uu[1]=uq.y; uu[2]=uq.z; uu[3]=uq.w; }
        float yo[4];
        #pragma unroll
        for (int i = 0; i < 4; i++){
            float2 Bq = *(const float2*)(Bp + (t+i)*NN);
            float2 Cq = *(const float2*)(Cp + (t+i)*NN);
            float du = dd[i] * uu[i];
            float a0 = __expf(dd[i] * A[0]);
            float a1 = __expf(dd[i] * A[1]);
            hc[0] = fmaf(a0, hc[0], du * Bq.x);
            hc[1] = fmaf(a1, hc[1], du * Bq.y);
            float p = fmaf(hc[1], Cq.y, hc[0] * Cq.x);
            p += __shfl_xor(p, 1);
            p += __shfl_xor(p, 2);
            p += __shfl_xor(p, 4);
            yo[i] = fmaf(uu[i], Dv, p);
        }
        if (ng == 0){
            float4 o; o.x = yo[0]; o.y = yo[1]; o.z = yo[2]; o.w = yo[3];
            *(float4*)(yp + t) = o;
        }
    }
}

__global__ __launch_bounds__(512) void k_scan_all(const float* __restrict__ x, const float* __restrict__ u2,
    const float* __restrict__ dt, const float* __restrict__ Bst, const float* __restrict__ Cst,
    const float* __restrict__ Alog, const float* __restrict__ Ds, float* __restrict__ ys){
    __shared__ float sA[SEG*SROW];
    __shared__ float sB[SEG*SROW];
    int blk = blockIdx.x;            // KK*BB*CC
    int k = blk / (BB*CC);
    int r = blk % (BB*CC);
    int d = r % CC; int b = r / CC;
    if (k == 0)      scan_body<0>(b, d, x,  dt, Bst, Cst, Alog, Ds, ys, sA, sB);
    else if (k == 1) scan_body<1>(b, d, x,  dt, Bst, Cst, Alog, Ds, ys, sA, sB);
    else             scan_body<2>(b, d, u2, dt, Bst, Cst, Alog, Ds, ys, sA, sB);
}

// ---------------- Kernel I: combine 3 paths + transpose to (B,L,C) ----------------
__global__ __launch_bounds__(256) void k_comb(const float* __restrict__ ys, const int* __restrict__ inv,
                                              float* __restrict__ out){
    int tile = blockIdx.x & 63; int b = blockIdx.x >> 6;
    int l0 = tile * 64;
    __shared__ float t0[CC * 65];
    __shared__ int invs[64];
    if (threadIdx.x < 64) invs[threadIdx.x] = inv[b*LL + l0 + threadIdx.x];
    __syncthreads();
    const float* y0p = ys + (size_t)(b*KK + 0) * CC * LL;
    const float* y1p = ys + (size_t)(b*KK + 1) * CC * LL;
    const float* y2p = ys + (size_t)(b*KK + 2) * CC * LL;
    for (int it = 0; it < 24; it++){
        int e = it * 256 + threadIdx.x;
        int li = e & 63; int c = e >> 6;
        int l = l0 + li;
        float v = y0p[(size_t)c*LL + l] + y1p[(size_t)c*LL + (LL-1-l)] + y2p[(size_t)c*LL + invs[li]];
        t0[c*65 + li] = v * (1.0f/3.0f);
    }
    __syncthreads();
    for (int it = 0; it < 24; it++){
        int e = it * 256 + threadIdx.x;
        int c = e % CC; int li = e / CC;
        out[((size_t)b*LL + l0 + li) * CC + c] = t0[c*65 + li];
    }
}

extern "C" void kernel_launch(void* const* d_in, const int* in_sizes, int n_in,
                              void* d_out, int out_size, void* d_ws, size_t ws_size,
                              hipStream_t stream){
    const float* x    = (const float*)d_in[0];
    const float* xpw  = (const float*)d_in[1];
    const float* dtw  = (const float*)d_in[2];
    const float* dtb  = (const float*)d_in[3];
    const float* Alog = (const float*)d_in[4];
    const float* Ds   = (const float*)d_in[5];
    const float* c1w  = (const float*)d_in[6];
    const float* c1b  = (const float*)d_in[7];
    const float* ca1w = (const float*)d_in[8];
    const float* ca1b = (const float*)d_in[9];
    const float* ca2w = (const float*)d_in[10];
    const float* ca2b = (const float*)d_in[11];
    const float* lng  = (const float*)d_in[12];
    const float* lnb  = (const float*)d_in[13];
    const float* c2w  = (const float*)d_in[14];
    const float* rpet = (const float*)d_in[15];
    float* out = (float*)d_out;

    float* ws   = (float*)d_ws;
    float* xc   = ws;                      // 384
    float* ca   = xc + 384;                // 384
    float* x1   = ca + 384;                // B*C*L = 1572864
    float* rpe  = x1 + (size_t)BB*CC*LL;   // C*L = 393216
    float* posy = rpe + (size_t)CC*LL;     // B*L
    float* posx = posy + (size_t)BB*LL;
    float* path = posx + (size_t)BB*LL;
    float* xd   = path + (size_t)BB*LL;    // B*C*L
    int*   idx  = (int*)(xd + (size_t)BB*CC*LL);   // B*L ints
    int*   inv  = idx + (size_t)BB*LL;             // B*L ints
    float* u2   = (float*)(inv + (size_t)BB*LL);   // B*C*L
    float* dtA  = u2 + (size_t)BB*CC*LL;           // B*K*C*L = 4718592
    float* Bst  = dtA + (size_t)BB*KK*CC*LL;       // B*K*L*N = 786432
    float* Cst  = Bst + (size_t)BB*KK*LL*NN;
    float* ysA  = Cst + (size_t)BB*KK*LL*NN;       // B*K*C*L

    k_mean  <<<BB*CC, 256, 0, stream>>>(x, xc);
    k_ca    <<<BB, 128, 0, stream>>>(xc, ca1w, ca1b, ca2w, ca2b, ca);
    k_conv  <<<(BB*CC*LL)/256, 256, 0, stream>>>(x, c1w, c1b, ca, x1);
    k_rpe   <<<(CC*LL)/256, 256, 0, stream>>>(rpet, rpe);
    k_off   <<<BB*64, 256, 0, stream>>>(x1, lng, lnb, c2w, posy, posx, path);
    k_sort  <<<BB, 1024, 0, stream>>>(path, idx, inv);
    k_sample<<<(BB*CC*LL)/256, 256, 0, stream>>>(x, rpe, posy, posx, xd);
    k_proj  <<<BB*KK*64, 192, 0, stream>>>(x, xd, idx, xpw, dtw, dtb, u2, dtA, Bst, Cst);
    k_scan_all<<<KK*BB*CC, 512, 0, stream>>>(x, u2, dtA, Bst, Cst, Alog, Ds, ysA);
    k_comb  <<<BB*64, 256, 0, stream>>>(ysA, inv, out);
}